// Round 2
// baseline (250.347 us; speedup 1.0000x reference)
//
#include <hip/hip_runtime.h>
#include <hip/hip_bf16.h>
#include <stdint.h>

// Problem constants
#define TSEQ   2048
#define DMODEL 1024
#define NHEAD  16
#define HDIM   64
#define MROWS  4096   // B*T

typedef __attribute__((ext_vector_type(8))) __bf16 bf16x8;
typedef __attribute__((ext_vector_type(4))) float f32x4;
typedef __attribute__((ext_vector_type(8))) unsigned short u16x8;

// log2(e)/8 : folds the 1/sqrt(64) logit scale into exp2
#define SC_LOG2E 0.18033688011112042f

#if __has_builtin(__builtin_amdgcn_exp2f)
#define EXP2F(x) __builtin_amdgcn_exp2f(x)
#else
#define EXP2F(x) __expf(0.6931471805599453f * (x))
#endif

__device__ __forceinline__ unsigned short f2bf(float f) {
    __hip_bfloat16 h = __float2bfloat16(f);
    return __builtin_bit_cast(unsigned short, h);
}
__device__ __forceinline__ float bf2f(unsigned short u) {
    union { unsigned int i; float f; } v;
    v.i = ((unsigned int)u) << 16;
    return v.f;
}

__device__ __forceinline__ void gld_lds16(const void* g, void* s) {
    __builtin_amdgcn_global_load_lds(
        (__attribute__((address_space(1))) void*)(void*)g,
        (__attribute__((address_space(3))) void*)s, 16, 0, 0);
}

// ---------------------------------------------------------------------------
// fp32 -> bf16 cast (vectorized)
// ---------------------------------------------------------------------------
__global__ void cast_f32_to_bf16(const float* __restrict__ in,
                                 unsigned short* __restrict__ out, int n4) {
    int i = blockIdx.x * blockDim.x + threadIdx.x;
    if (i < n4) {
        float4 v = ((const float4*)in)[i];
        ushort4 u;
        u.x = f2bf(v.x); u.y = f2bf(v.y); u.z = f2bf(v.z); u.w = f2bf(v.w);
        ((ushort4*)out)[i] = u;
    }
}

// ---------------------------------------------------------------------------
// GEMM: C[m,n] = sum_k A[m,k] * B[n,k]   (A:[M,K] bf16, B:[N,K] bf16)
// m97 structure: 128x128 tile, BK=32, 4 waves (2x2), 16x16x32 MFMA.
// ---------------------------------------------------------------------------
template<bool STORE_F32>
__global__ __launch_bounds__(256, 2)
void gemm_bt(const unsigned short* __restrict__ A,
             const unsigned short* __restrict__ B,
             void* __restrict__ C, int M, int N, int K) {
    (void)M;
    __shared__ unsigned short As[128 * 32];
    __shared__ unsigned short Bs[128 * 32];
    const int tid = threadIdx.x;
    const int nb = N >> 7;
    const int bm = blockIdx.x / nb;
    const int bn = blockIdx.x % nb;
    const int w  = tid >> 6, l = tid & 63;
    const int wr = w >> 1,  wc = w & 1;
    const int lr = l & 15,  lg = l >> 4;

    f32x4 acc[4][4] = {};

    const unsigned short* Ab = A + (size_t)bm * 128 * K;
    const unsigned short* Bb = B + (size_t)bn * 128 * K;

    const int c0 = tid, c1 = tid + 256;
    const int ar0 = c0 >> 2, ak0 = (c0 & 3) * 8;
    const int ar1 = c1 >> 2, ak1 = (c1 & 3) * 8;

    for (int kt = 0; kt < K; kt += 32) {
        __syncthreads();
        gld_lds16(Ab + (size_t)ar0 * K + kt + ak0, As + c0 * 8);
        gld_lds16(Ab + (size_t)ar1 * K + kt + ak1, As + c1 * 8);
        gld_lds16(Bb + (size_t)ar0 * K + kt + ak0, Bs + c0 * 8);
        gld_lds16(Bb + (size_t)ar1 * K + kt + ak1, Bs + c1 * 8);
        __syncthreads();

        bf16x8 af[4], bfr[4];
#pragma unroll
        for (int i = 0; i < 4; i++)
            af[i] = *(const bf16x8*)(As + (wr * 64 + i * 16 + lr) * 32 + lg * 8);
#pragma unroll
        for (int i = 0; i < 4; i++)
            bfr[i] = *(const bf16x8*)(Bs + (wc * 64 + i * 16 + lr) * 32 + lg * 8);
#pragma unroll
        for (int mi = 0; mi < 4; mi++)
#pragma unroll
            for (int ni = 0; ni < 4; ni++)
                acc[mi][ni] = __builtin_amdgcn_mfma_f32_16x16x32_bf16(
                    af[mi], bfr[ni], acc[mi][ni], 0, 0, 0);
    }

    const int row0 = bm * 128 + wr * 64;
    const int col0 = bn * 128 + wc * 64;
#pragma unroll
    for (int mi = 0; mi < 4; mi++)
#pragma unroll
        for (int ni = 0; ni < 4; ni++)
#pragma unroll
            for (int r = 0; r < 4; r++) {
                const int row = row0 + mi * 16 + lg * 4 + r;
                const int col = col0 + ni * 16 + lr;
                if (STORE_F32)
                    ((float*)C)[(size_t)row * N + col] = acc[mi][ni][r];
                else
                    ((unsigned short*)C)[(size_t)row * N + col] = f2bf(acc[mi][ni][r]);
            }
}

// ---------------------------------------------------------------------------
// Tile-granular V suffix sums: tsuf[b][h][t][d] = sum_{rows in tiles > t} V[row][d]
// 32 blocks (one per b,h), 64 threads (one per d).
// ---------------------------------------------------------------------------
__global__ void vsuf_kernel(const unsigned short* __restrict__ qkv,
                            float* __restrict__ tsuf) {
    const int bh = blockIdx.x, b = bh >> 4, h = bh & 15;
    const int d = threadIdx.x;
    const unsigned short* vb =
        qkv + ((size_t)b * TSEQ) * 3072 + 2048 + h * 64 + d;
    float a0 = 0.f, a1 = 0.f, a2 = 0.f, a3 = 0.f;
    for (int t = 31; t >= 0; t--) {
        tsuf[((size_t)bh * 32 + t) * 64 + d] = a0 + a1 + a2 + a3;
        const unsigned short* vt = vb + (size_t)(t * 64) * 3072;
#pragma unroll
        for (int r = 0; r < 64; r += 4) {
            a0 += bf2f(vt[(size_t)(r + 0) * 3072]);
            a1 += bf2f(vt[(size_t)(r + 1) * 3072]);
            a2 += bf2f(vt[(size_t)(r + 2) * 3072]);
            a3 += bf2f(vt[(size_t)(r + 3) * 3072]);
        }
    }
}

// ---------------------------------------------------------------------------
// Attention v2: causal-skip + fixed m=0 + prefetch-staged double-buffered V^T.
// qkv [4096][3072] bf16 (q|k|v), out [4096][1024] bf16.
// Block = (b,h,q-tile of 64); processes k-tiles 0..qt only; future-k handled
// in closed form via tsuf (masked logits are 0 -> uniform weight exp(0)=1).
// ---------------------------------------------------------------------------
__global__ __launch_bounds__(256, 2)
void attn_kernel(const unsigned short* __restrict__ qkv,
                 const float* __restrict__ tsuf,
                 unsigned short* __restrict__ out) {
    __shared__ unsigned short VT[2][64 * 72];   // V^T tiles (double-buffered)
    __shared__ unsigned short Pl[4][16 * 72];   // per-wave P tile

    const int tid = threadIdx.x;
    const int w = tid >> 6, l = tid & 63, lr = l & 15, lg = l >> 4;
    const int bid = blockIdx.x;
    const int qt = 31 - (bid & 31);   // heavy q-tiles dispatch first
    const int h  = (bid >> 5) & 15;
    const int b  = bid >> 9;
    const int bh = b * 16 + h;

    const size_t rowbase = (size_t)b * TSEQ;

    // Q fragments (A-operand): row = lr, k = lg*8.. ; two 32-wide k-steps
    const unsigned short* qp =
        qkv + (rowbase + qt * 64 + w * 16 + lr) * 3072 + h * 64 + lg * 8;
    const bf16x8 qf0 = *(const bf16x8*)qp;
    const bf16x8 qf1 = *(const bf16x8*)(qp + 32);

    f32x4 o[4] = {};
    float rsum[4] = {0.f, 0.f, 0.f, 0.f};
    const int qrow = qt * 64 + w * 16 + lg * 4;  // + r

    const int vr = tid & 63, vcg = tid >> 6;
    const unsigned short* vbase = qkv + (rowbase + vr) * 3072 + 2048 + h * 64 + vcg * 16;

    // prologue: stage V^T tile 0
    {
        u16x8 v0 = *(const u16x8*)vbase;
        u16x8 v1 = *(const u16x8*)(vbase + 8);
#pragma unroll
        for (int i = 0; i < 8; i++) VT[0][(vcg * 16 + i) * 72 + vr] = v0[i];
#pragma unroll
        for (int i = 0; i < 8; i++) VT[0][(vcg * 16 + 8 + i) * 72 + vr] = v1[i];
    }
    __syncthreads();

    int cur = 0;
    for (int kt = 0; kt <= qt; kt++) {
        // prefetch next V tile into registers (latency hides under compute)
        u16x8 nv0, nv1;
        const bool pf = (kt < qt);
        if (pf) {
            const unsigned short* vp = vbase + (size_t)((kt + 1) * 64) * 3072;
            nv0 = *(const u16x8*)vp;
            nv1 = *(const u16x8*)(vp + 8);
        }

        // S = Q K^T, scaled into exp2 domain
        float pv[4][4];
#pragma unroll
        for (int f = 0; f < 4; f++) {
            const unsigned short* kp =
                qkv + (rowbase + kt * 64 + f * 16 + lr) * 3072 + 1024 + h * 64 + lg * 8;
            bf16x8 kb0 = *(const bf16x8*)kp;
            bf16x8 kb1 = *(const bf16x8*)(kp + 32);
            f32x4 z = {0.f, 0.f, 0.f, 0.f};
            f32x4 s = __builtin_amdgcn_mfma_f32_16x16x32_bf16(qf0, kb0, z, 0, 0, 0);
            s = __builtin_amdgcn_mfma_f32_16x16x32_bf16(qf1, kb1, s, 0, 0, 0);
#pragma unroll
            for (int r = 0; r < 4; r++) pv[f][r] = s[r] * SC_LOG2E;
        }
        if (kt == qt) {  // diagonal tile: tril zeroing (exp2(0)=1, faithful)
#pragma unroll
            for (int f = 0; f < 4; f++) {
                const int kcol = kt * 64 + f * 16 + lr;
#pragma unroll
                for (int r = 0; r < 4; r++)
                    if (kcol > qrow + r) pv[f][r] = 0.f;
            }
        }

        // P = exp2(pv); lane-local row-sum partials; pack to bf16
        unsigned short* pw = &Pl[w][0];
#pragma unroll
        for (int f = 0; f < 4; f++)
#pragma unroll
            for (int r = 0; r < 4; r++) {
                float p = EXP2F(pv[f][r]);
                rsum[r] += p;
                pw[(lg * 4 + r) * 72 + f * 16 + lr] = f2bf(p);
            }

        // P (same-wave LDS roundtrip to A-layout)
        bf16x8 pa0 = *(const bf16x8*)(pw + lr * 72 + lg * 8);
        bf16x8 pa1 = *(const bf16x8*)(pw + lr * 72 + 32 + lg * 8);
        const unsigned short* vtc = &VT[cur][0];
#pragma unroll
        for (int f2 = 0; f2 < 4; f2++) {
            bf16x8 vb0 = *(const bf16x8*)(vtc + (f2 * 16 + lr) * 72 + lg * 8);
            bf16x8 vb1 = *(const bf16x8*)(vtc + (f2 * 16 + lr) * 72 + 32 + lg * 8);
            o[f2] = __builtin_amdgcn_mfma_f32_16x16x32_bf16(pa0, vb0, o[f2], 0, 0, 0);
            o[f2] = __builtin_amdgcn_mfma_f32_16x16x32_bf16(pa1, vb1, o[f2], 0, 0, 0);
        }

        // write prefetched V^T into the other buffer
        if (pf) {
            unsigned short* vtn = &VT[cur ^ 1][0];
#pragma unroll
            for (int i = 0; i < 8; i++) vtn[(vcg * 16 + i) * 72 + vr] = nv0[i];
#pragma unroll
            for (int i = 0; i < 8; i++) vtn[(vcg * 16 + 8 + i) * 72 + vr] = nv1[i];
        }
        __syncthreads();
        cur ^= 1;
    }

    // row-sum reduce over the 16 lanes sharing a row (lr dimension)
#pragma unroll
    for (int d = 1; d < 16; d <<= 1)
#pragma unroll
        for (int r = 0; r < 4; r++)
            rsum[r] += __shfl_xor(rsum[r], d);

    // epilogue: add closed-form future-k contribution, normalize, store
    const float nmask = (float)((31 - qt) * 64);
    const float* tp = tsuf + ((size_t)bh * 32 + qt) * 64;
#pragma unroll
    for (int r = 0; r < 4; r++) {
        const float inv = 1.f / (rsum[r] + nmask);
#pragma unroll
        for (int f2 = 0; f2 < 4; f2++) {
            float num = o[f2][r] + tp[f2 * 16 + lr];
            out[(rowbase + qrow + r) * 1024 + h * 64 + f2 * 16 + lr] =
                f2bf(num * inv);
        }
    }
}

// ---------------------------------------------------------------------------
extern "C" void kernel_launch(void* const* d_in, const int* in_sizes, int n_in,
                              void* d_out, int out_size, void* d_ws, size_t ws_size,
                              hipStream_t stream) {
    const float* x     = (const float*)d_in[0];
    const float* w_in  = (const float*)d_in[1];
    const float* w_out = (const float*)d_in[2];

    unsigned short* ws  = (unsigned short*)d_ws;
    unsigned short* xb  = ws;                            // 4096*1024
    unsigned short* wib = xb  + (size_t)4096 * 1024;     // 3072*1024
    unsigned short* wob = wib + (size_t)3072 * 1024;     // 1024*1024
    unsigned short* qkv = wob + (size_t)1024 * 1024;     // 4096*3072
    unsigned short* ao  = qkv + (size_t)4096 * 3072;     // 4096*1024
    float* tsuf = (float*)(ao + (size_t)4096 * 1024);    // 2*16*32*64 floats

    cast_f32_to_bf16<<<4096, 256, 0, stream>>>(x, xb, 4096 * 1024 / 4);
    cast_f32_to_bf16<<<3072, 256, 0, stream>>>(w_in, wib, 3072 * 1024 / 4);
    cast_f32_to_bf16<<<1024, 256, 0, stream>>>(w_out, wob, 1024 * 1024 / 4);

    gemm_bt<false><<<(4096 / 128) * (3072 / 128), 256, 0, stream>>>(
        xb, wib, qkv, 4096, 3072, 1024);
    vsuf_kernel<<<32, 64, 0, stream>>>(qkv, tsuf);
    attn_kernel<<<2 * 16 * (TSEQ / 64), 256, 0, stream>>>(qkv, tsuf, ao);
    gemm_bt<true><<<(4096 / 128) * (1024 / 128), 256, 0, stream>>>(
        ao, wob, (float*)d_out, 4096, 1024, 1024);
}

// Round 3
// 184.329 us; speedup vs baseline: 1.3582x; 1.3582x over previous
//
#include <hip/hip_runtime.h>
#include <hip/hip_bf16.h>
#include <stdint.h>

// Problem constants
#define TSEQ   2048
#define DMODEL 1024
#define NHEAD  16
#define HDIM   64

typedef __attribute__((ext_vector_type(8))) __bf16 bf16x8;
typedef __attribute__((ext_vector_type(4))) float f32x4;
typedef __attribute__((ext_vector_type(8))) unsigned short u16x8;

// log2(e)/8 : folds the 1/sqrt(64) logit scale into exp2
#define SC_LOG2E 0.18033688011112042f

#if __has_builtin(__builtin_amdgcn_exp2f)
#define EXP2F(x) __builtin_amdgcn_exp2f(x)
#else
#define EXP2F(x) __expf(0.6931471805599453f * (x))
#endif

__device__ __forceinline__ unsigned short f2bf(float f) {
    __hip_bfloat16 h = __float2bfloat16(f);
    return __builtin_bit_cast(unsigned short, h);
}
__device__ __forceinline__ float bf2f(unsigned short u) {
    union { unsigned int i; float f; } v;
    v.i = ((unsigned int)u) << 16;
    return v.f;
}

__device__ __forceinline__ void gld_lds16(const void* g, void* s) {
    __builtin_amdgcn_global_load_lds(
        (__attribute__((address_space(1))) void*)(void*)g,
        (__attribute__((address_space(3))) void*)s, 16, 0, 0);
}

// ---------------------------------------------------------------------------
// fp32 -> bf16 cast (vectorized)
// ---------------------------------------------------------------------------
__global__ void cast_f32_to_bf16(const float* __restrict__ in,
                                 unsigned short* __restrict__ out, int n4) {
    int i = blockIdx.x * blockDim.x + threadIdx.x;
    if (i < n4) {
        float4 v = ((const float4*)in)[i];
        ushort4 u;
        u.x = f2bf(v.x); u.y = f2bf(v.y); u.z = f2bf(v.z); u.w = f2bf(v.w);
        ((ushort4*)out)[i] = u;
    }
}

// ---------------------------------------------------------------------------
// GEMM: C[m,n] = sum_k A[m,k] * B[n,k]   (A:[M,K] bf16, B:[N,K] bf16)
// ---------------------------------------------------------------------------
template<bool STORE_F32>
__global__ __launch_bounds__(256, 2)
void gemm_bt(const unsigned short* __restrict__ A,
             const unsigned short* __restrict__ B,
             void* __restrict__ C, int M, int N, int K) {
    (void)M;
    __shared__ unsigned short As[128 * 32];
    __shared__ unsigned short Bs[128 * 32];
    const int tid = threadIdx.x;
    const int nb = N >> 7;
    const int bm = blockIdx.x / nb;
    const int bn = blockIdx.x % nb;
    const int w  = tid >> 6, l = tid & 63;
    const int wr = w >> 1,  wc = w & 1;
    const int lr = l & 15,  lg = l >> 4;

    f32x4 acc[4][4] = {};

    const unsigned short* Ab = A + (size_t)bm * 128 * K;
    const unsigned short* Bb = B + (size_t)bn * 128 * K;

    const int c0 = tid, c1 = tid + 256;
    const int ar0 = c0 >> 2, ak0 = (c0 & 3) * 8;
    const int ar1 = c1 >> 2, ak1 = (c1 & 3) * 8;

    for (int kt = 0; kt < K; kt += 32) {
        __syncthreads();
        gld_lds16(Ab + (size_t)ar0 * K + kt + ak0, As + c0 * 8);
        gld_lds16(Ab + (size_t)ar1 * K + kt + ak1, As + c1 * 8);
        gld_lds16(Bb + (size_t)ar0 * K + kt + ak0, Bs + c0 * 8);
        gld_lds16(Bb + (size_t)ar1 * K + kt + ak1, Bs + c1 * 8);
        __syncthreads();

        bf16x8 af[4], bfr[4];
#pragma unroll
        for (int i = 0; i < 4; i++)
            af[i] = *(const bf16x8*)(As + (wr * 64 + i * 16 + lr) * 32 + lg * 8);
#pragma unroll
        for (int i = 0; i < 4; i++)
            bfr[i] = *(const bf16x8*)(Bs + (wc * 64 + i * 16 + lr) * 32 + lg * 8);
#pragma unroll
        for (int mi = 0; mi < 4; mi++)
#pragma unroll
            for (int ni = 0; ni < 4; ni++)
                acc[mi][ni] = __builtin_amdgcn_mfma_f32_16x16x32_bf16(
                    af[mi], bfr[ni], acc[mi][ni], 0, 0, 0);
    }

    const int row0 = bm * 128 + wr * 64;
    const int col0 = bn * 128 + wc * 64;
#pragma unroll
    for (int mi = 0; mi < 4; mi++)
#pragma unroll
        for (int ni = 0; ni < 4; ni++)
#pragma unroll
            for (int r = 0; r < 4; r++) {
                const int row = row0 + mi * 16 + lg * 4 + r;
                const int col = col0 + ni * 16 + lr;
                if (STORE_F32)
                    ((float*)C)[(size_t)row * N + col] = acc[mi][ni][r];
                else
                    ((unsigned short*)C)[(size_t)row * N + col] = f2bf(acc[mi][ni][r]);
            }
}

// ---------------------------------------------------------------------------
// V transpose: VTg[bh][d][k] = V[b][k][h*64+d]   (LDS-tiled, coalesced)
// grid = 32 bh * 32 ktiles, 256 threads.
// ---------------------------------------------------------------------------
__global__ __launch_bounds__(256)
void vtran_kernel(const unsigned short* __restrict__ qkv,
                  unsigned short* __restrict__ vtg) {
    __shared__ unsigned short T[64][72];
    const int bid = blockIdx.x;
    const int kb_ = bid & 31;
    const int bh  = bid >> 5;
    const int b = bh >> 4, h = bh & 15;
    const int tid = threadIdx.x;

    const int r = tid >> 2, cq = (tid & 3) * 16;
    const unsigned short* src =
        qkv + ((size_t)(b * TSEQ + kb_ * 64 + r)) * 3072 + 2048 + h * 64 + cq;
    u16x8 v0 = *(const u16x8*)src;
    u16x8 v1 = *(const u16x8*)(src + 8);
#pragma unroll
    for (int i = 0; i < 8; i++) T[r][cq + i] = v0[i];
#pragma unroll
    for (int i = 0; i < 8; i++) T[r][cq + 8 + i] = v1[i];
    __syncthreads();

    const int d = tid >> 2, kq = (tid & 3) * 16;
    u16x8 o0, o1;
#pragma unroll
    for (int i = 0; i < 8; i++) o0[i] = T[kq + i][d];
#pragma unroll
    for (int i = 0; i < 8; i++) o1[i] = T[kq + 8 + i][d];
    unsigned short* dst = vtg + ((size_t)bh * 64 + d) * TSEQ + kb_ * 64 + kq;
    *(u16x8*)dst = o0;
    *(u16x8*)(dst + 8) = o1;
}

// ---------------------------------------------------------------------------
// Tile-granular V suffix sums: tsuf[bh][t][d] = sum over rows in tiles > t
// ---------------------------------------------------------------------------
__global__ void vsuf_kernel(const unsigned short* __restrict__ qkv,
                            float* __restrict__ tsuf) {
    const int bh = blockIdx.x, b = bh >> 4, h = bh & 15;
    const int d = threadIdx.x;
    const unsigned short* vb =
        qkv + ((size_t)b * TSEQ) * 3072 + 2048 + h * 64 + d;
    float a0 = 0.f, a1 = 0.f, a2 = 0.f, a3 = 0.f;
    for (int t = 31; t >= 0; t--) {
        tsuf[((size_t)bh * 32 + t) * 64 + d] = a0 + a1 + a2 + a3;
        const unsigned short* vt = vb + (size_t)(t * 64) * 3072;
#pragma unroll
        for (int r = 0; r < 64; r += 4) {
            a0 += bf2f(vt[(size_t)(r + 0) * 3072]);
            a1 += bf2f(vt[(size_t)(r + 1) * 3072]);
            a2 += bf2f(vt[(size_t)(r + 2) * 3072]);
            a3 += bf2f(vt[(size_t)(r + 3) * 3072]);
        }
    }
}

// ---------------------------------------------------------------------------
// Attention v3: barrier-free 1-wave blocks, 32 q-rows/wave.
// K double-buffered in regs (issued 1 tile early); V^T frags loaded directly
// from pre-transposed global (issued at iter top, consumed after S/exp).
// LDS: only the per-wave 32x72 P tile. Heavy-first + XCD-pinned (b,h).
// ---------------------------------------------------------------------------
struct AttCtx {
    const unsigned short* kb0;
    const unsigned short* vb0;
    unsigned short* Pl;
    int lr, lg, qrow0, lastkt;
};

__device__ __forceinline__ void att_body(
    const AttCtx& c, int kt,
    const bf16x8 (&qf)[2][2], bf16x8 (&kC)[4][2], bf16x8 (&kN)[4][2],
    f32x4 (&o)[2][4], float (&rsum)[2][4]) {

    // V^T frags for THIS tile: issue now, consume after S/exp (~400cy later)
    bf16x8 vt[4][2];
#pragma unroll
    for (int f2 = 0; f2 < 4; f2++) {
        const unsigned short* vp =
            c.vb0 + (size_t)(f2 * 16 + c.lr) * TSEQ + kt * 64 + c.lg * 8;
        vt[f2][0] = *(const bf16x8*)vp;
        vt[f2][1] = *(const bf16x8*)(vp + 32);
    }
    // K frags for NEXT tile: in flight for a full iteration
    if (kt < c.lastkt) {
#pragma unroll
        for (int f = 0; f < 4; f++) {
            const unsigned short* kp =
                c.kb0 + (size_t)((kt + 1) * 64 + f * 16 + c.lr) * 3072 + c.lg * 8;
            kN[f][0] = *(const bf16x8*)kp;
            kN[f][1] = *(const bf16x8*)(kp + 32);
        }
    }

    // S = Q K^T (uses kC loaded one iteration ago)
    float pvv[2][4][4];
#pragma unroll
    for (int mi = 0; mi < 2; mi++)
#pragma unroll
        for (int f = 0; f < 4; f++) {
            f32x4 z = {0.f, 0.f, 0.f, 0.f};
            f32x4 s = __builtin_amdgcn_mfma_f32_16x16x32_bf16(qf[mi][0], kC[f][0], z, 0, 0, 0);
            s = __builtin_amdgcn_mfma_f32_16x16x32_bf16(qf[mi][1], kC[f][1], s, 0, 0, 0);
#pragma unroll
            for (int r = 0; r < 4; r++) pvv[mi][f][r] = s[r] * SC_LOG2E;
        }

    if (kt == c.lastkt) {  // diagonal tile: tril zeroing (exp2(0)=1, faithful)
#pragma unroll
        for (int mi = 0; mi < 2; mi++)
#pragma unroll
            for (int f = 0; f < 4; f++) {
                const int kcol = kt * 64 + f * 16 + c.lr;
#pragma unroll
                for (int r = 0; r < 4; r++)
                    if (kcol > c.qrow0 + mi * 16 + c.lg * 4 + r) pvv[mi][f][r] = 0.f;
            }
    }

    // P = exp2; lane-local row-sums; pack to per-wave LDS tile (D->A relayout)
#pragma unroll
    for (int mi = 0; mi < 2; mi++)
#pragma unroll
        for (int f = 0; f < 4; f++)
#pragma unroll
            for (int r = 0; r < 4; r++) {
                float p = EXP2F(pvv[mi][f][r]);
                rsum[mi][r] += p;
                c.Pl[(mi * 16 + c.lg * 4 + r) * 72 + f * 16 + c.lr] = f2bf(p);
            }

    bf16x8 pa[2][2];
#pragma unroll
    for (int mi = 0; mi < 2; mi++) {
        pa[mi][0] = *(const bf16x8*)(c.Pl + (mi * 16 + c.lr) * 72 + c.lg * 8);
        pa[mi][1] = *(const bf16x8*)(c.Pl + (mi * 16 + c.lr) * 72 + 32 + c.lg * 8);
    }
#pragma unroll
    for (int mi = 0; mi < 2; mi++)
#pragma unroll
        for (int f2 = 0; f2 < 4; f2++) {
            o[mi][f2] = __builtin_amdgcn_mfma_f32_16x16x32_bf16(pa[mi][0], vt[f2][0], o[mi][f2], 0, 0, 0);
            o[mi][f2] = __builtin_amdgcn_mfma_f32_16x16x32_bf16(pa[mi][1], vt[f2][1], o[mi][f2], 0, 0, 0);
        }
}

__global__ __launch_bounds__(64, 2)
void attn_kernel(const unsigned short* __restrict__ qkv,
                 const unsigned short* __restrict__ vtg,
                 const float* __restrict__ tsuf,
                 unsigned short* __restrict__ out) {
    __shared__ unsigned short Pl[32 * 72];

    const int l = threadIdx.x, lr = l & 15, lg = l >> 4;
    const int bid = blockIdx.x;
    // XCD pinning: bid%8 -> XCD owns bh in {4x..4x+3}; heavy waves first.
    const int bh = (bid & 7) * 4 + ((bid >> 3) & 3);
    const int wq = 63 - (bid >> 5);
    const int b = bh >> 4, h = bh & 15;
    const int qrow0 = wq * 32;
    const int lastkt = wq >> 1;
    const size_t rowbase = (size_t)b * TSEQ;

    bf16x8 qf[2][2];
#pragma unroll
    for (int mi = 0; mi < 2; mi++) {
        const unsigned short* qp =
            qkv + (rowbase + qrow0 + mi * 16 + lr) * 3072 + h * 64 + lg * 8;
        qf[mi][0] = *(const bf16x8*)qp;
        qf[mi][1] = *(const bf16x8*)(qp + 32);
    }

    AttCtx c;
    c.kb0 = qkv + rowbase * 3072 + 1024 + h * 64;
    c.vb0 = vtg + (size_t)bh * 64 * TSEQ;
    c.Pl = Pl;
    c.lr = lr; c.lg = lg; c.qrow0 = qrow0; c.lastkt = lastkt;

    f32x4 o[2][4] = {};
    float rsum[2][4] = {};

    bf16x8 kA[4][2], kB[4][2];
#pragma unroll
    for (int f = 0; f < 4; f++) {
        const unsigned short* kp = c.kb0 + (size_t)(f * 16 + lr) * 3072 + lg * 8;
        kA[f][0] = *(const bf16x8*)kp;
        kA[f][1] = *(const bf16x8*)(kp + 32);
    }

    int kt = 0;
    for (;;) {
        att_body(c, kt, qf, kA, kB, o, rsum);
        if (kt == lastkt) break;
        ++kt;
        att_body(c, kt, qf, kB, kA, o, rsum);
        if (kt == lastkt) break;
        ++kt;
    }

    // row-sum reduce over the 16 lanes sharing a row
#pragma unroll
    for (int d = 1; d < 16; d <<= 1)
#pragma unroll
        for (int mi = 0; mi < 2; mi++)
#pragma unroll
            for (int r = 0; r < 4; r++)
                rsum[mi][r] += __shfl_xor(rsum[mi][r], d);

    // epilogue: closed-form future-k part, normalize, store
    const float nmask = (float)((31 - lastkt) * 64);
    const float* tp = tsuf + ((size_t)bh * 32 + lastkt) * 64;
#pragma unroll
    for (int mi = 0; mi < 2; mi++)
#pragma unroll
        for (int r = 0; r < 4; r++) {
            const float inv = 1.f / (rsum[mi][r] + nmask);
#pragma unroll
            for (int f2 = 0; f2 < 4; f2++) {
                float num = o[mi][f2][r] + tp[f2 * 16 + lr];
                out[(rowbase + qrow0 + mi * 16 + lg * 4 + r) * 1024 + h * 64 + f2 * 16 + lr] =
                    f2bf(num * inv);
            }
        }
}

// ---------------------------------------------------------------------------
extern "C" void kernel_launch(void* const* d_in, const int* in_sizes, int n_in,
                              void* d_out, int out_size, void* d_ws, size_t ws_size,
                              hipStream_t stream) {
    const float* x     = (const float*)d_in[0];
    const float* w_in  = (const float*)d_in[1];
    const float* w_out = (const float*)d_in[2];

    unsigned short* ws  = (unsigned short*)d_ws;
    unsigned short* xb  = ws;                            // 4096*1024
    unsigned short* wib = xb  + (size_t)4096 * 1024;     // 3072*1024
    unsigned short* wob = wib + (size_t)3072 * 1024;     // 1024*1024
    unsigned short* qkv = wob + (size_t)1024 * 1024;     // 4096*3072
    unsigned short* ao  = qkv + (size_t)4096 * 3072;     // 4096*1024
    float* tsuf = (float*)(ao + (size_t)4096 * 1024);    // 32*32*64 f32
    unsigned short* vtg = (unsigned short*)(tsuf + 32 * 32 * 64); // 32*64*2048

    cast_f32_to_bf16<<<4096, 256, 0, stream>>>(x, xb, 4096 * 1024 / 4);
    cast_f32_to_bf16<<<3072, 256, 0, stream>>>(w_in, wib, 3072 * 1024 / 4);
    cast_f32_to_bf16<<<1024, 256, 0, stream>>>(w_out, wob, 1024 * 1024 / 4);

    gemm_bt<false><<<(4096 / 128) * (3072 / 128), 256, 0, stream>>>(
        xb, wib, qkv, 4096, 3072, 1024);
    vtran_kernel<<<32 * 32, 256, 0, stream>>>(qkv, vtg);
    vsuf_kernel<<<32, 64, 0, stream>>>(qkv, tsuf);
    attn_kernel<<<2048, 64, 0, stream>>>(qkv, vtg, tsuf, ao);
    gemm_bt<true><<<(4096 / 128) * (1024 / 128), 256, 0, stream>>>(
        ao, wob, (float*)d_out, 4096, 1024, 1024);
}

// Round 4
// 129.035 us; speedup vs baseline: 1.9401x; 1.4285x over previous
//
#include <hip/hip_runtime.h>
#include <hip/hip_bf16.h>
#include <stdint.h>

// Problem constants
#define TSEQ   2048
#define DMODEL 1024
#define NHEAD  16
#define HDIM   64

typedef __attribute__((ext_vector_type(8))) __bf16 bf16x8;
typedef __attribute__((ext_vector_type(4))) float f32x4;
typedef __attribute__((ext_vector_type(8))) unsigned short u16x8;

// log2(e)/8 : folds the 1/sqrt(64) logit scale into exp2
#define SC_LOG2E 0.18033688011112042f

#if __has_builtin(__builtin_amdgcn_exp2f)
#define EXP2F(x) __builtin_amdgcn_exp2f(x)
#else
#define EXP2F(x) __expf(0.6931471805599453f * (x))
#endif

__device__ __forceinline__ unsigned short f2bf(float f) {
    __hip_bfloat16 h = __float2bfloat16(f);
    return __builtin_bit_cast(unsigned short, h);
}
__device__ __forceinline__ float bf2f(unsigned short u) {
    union { unsigned int i; float f; } v;
    v.i = ((unsigned int)u) << 16;
    return v.f;
}

__device__ __forceinline__ void gld_lds16(const void* g, void* s) {
    __builtin_amdgcn_global_load_lds(
        (__attribute__((address_space(1))) void*)(void*)g,
        (__attribute__((address_space(3))) void*)s, 16, 0, 0);
}

// ---------------------------------------------------------------------------
// fp32 -> bf16 cast (vectorized)
// ---------------------------------------------------------------------------
__global__ void cast_f32_to_bf16(const float* __restrict__ in,
                                 unsigned short* __restrict__ out, int n4) {
    int i = blockIdx.x * blockDim.x + threadIdx.x;
    if (i < n4) {
        float4 v = ((const float4*)in)[i];
        ushort4 u;
        u.x = f2bf(v.x); u.y = f2bf(v.y); u.z = f2bf(v.z); u.w = f2bf(v.w);
        ((ushort4*)out)[i] = u;
    }
}

// ---------------------------------------------------------------------------
// GEMM: C[m,n] = sum_k A[m,k] * B[n,k]   (A:[M,K] bf16, B:[N,K] bf16)
// ---------------------------------------------------------------------------
template<bool STORE_F32>
__global__ __launch_bounds__(256, 2)
void gemm_bt(const unsigned short* __restrict__ A,
             const unsigned short* __restrict__ B,
             void* __restrict__ C, int M, int N, int K) {
    (void)M;
    __shared__ unsigned short As[128 * 32];
    __shared__ unsigned short Bs[128 * 32];
    const int tid = threadIdx.x;
    const int nb = N >> 7;
    const int bm = blockIdx.x / nb;
    const int bn = blockIdx.x % nb;
    const int w  = tid >> 6, l = tid & 63;
    const int wr = w >> 1,  wc = w & 1;
    const int lr = l & 15,  lg = l >> 4;

    f32x4 acc[4][4] = {};

    const unsigned short* Ab = A + (size_t)bm * 128 * K;
    const unsigned short* Bb = B + (size_t)bn * 128 * K;

    const int c0 = tid, c1 = tid + 256;
    const int ar0 = c0 >> 2, ak0 = (c0 & 3) * 8;
    const int ar1 = c1 >> 2, ak1 = (c1 & 3) * 8;

    for (int kt = 0; kt < K; kt += 32) {
        __syncthreads();
        gld_lds16(Ab + (size_t)ar0 * K + kt + ak0, As + c0 * 8);
        gld_lds16(Ab + (size_t)ar1 * K + kt + ak1, As + c1 * 8);
        gld_lds16(Bb + (size_t)ar0 * K + kt + ak0, Bs + c0 * 8);
        gld_lds16(Bb + (size_t)ar1 * K + kt + ak1, Bs + c1 * 8);
        __syncthreads();

        bf16x8 af[4], bfr[4];
#pragma unroll
        for (int i = 0; i < 4; i++)
            af[i] = *(const bf16x8*)(As + (wr * 64 + i * 16 + lr) * 32 + lg * 8);
#pragma unroll
        for (int i = 0; i < 4; i++)
            bfr[i] = *(const bf16x8*)(Bs + (wc * 64 + i * 16 + lr) * 32 + lg * 8);
#pragma unroll
        for (int mi = 0; mi < 4; mi++)
#pragma unroll
            for (int ni = 0; ni < 4; ni++)
                acc[mi][ni] = __builtin_amdgcn_mfma_f32_16x16x32_bf16(
                    af[mi], bfr[ni], acc[mi][ni], 0, 0, 0);
    }

    const int row0 = bm * 128 + wr * 64;
    const int col0 = bn * 128 + wc * 64;
#pragma unroll
    for (int mi = 0; mi < 4; mi++)
#pragma unroll
        for (int ni = 0; ni < 4; ni++)
#pragma unroll
            for (int r = 0; r < 4; r++) {
                const int row = row0 + mi * 16 + lg * 4 + r;
                const int col = col0 + ni * 16 + lr;
                if (STORE_F32)
                    ((float*)C)[(size_t)row * N + col] = acc[mi][ni][r];
                else
                    ((unsigned short*)C)[(size_t)row * N + col] = f2bf(acc[mi][ni][r]);
            }
}

// ---------------------------------------------------------------------------
// V transpose + per-tile column sums:
//   VTg[bh][d][k] = V[b][k][h*64+d]
//   ts[bh][t][d]  = sum_{k in tile t} V[k][d]
// grid = 32 bh * 32 ktiles, 256 threads.
// ---------------------------------------------------------------------------
__global__ __launch_bounds__(256)
void vtran_kernel(const unsigned short* __restrict__ qkv,
                  unsigned short* __restrict__ vtg,
                  float* __restrict__ ts) {
    __shared__ unsigned short T[64][72];
    const int bid = blockIdx.x;
    const int kb_ = bid & 31;
    const int bh  = bid >> 5;
    const int b = bh >> 4, h = bh & 15;
    const int tid = threadIdx.x;

    const int r = tid >> 2, cq = (tid & 3) * 16;
    const unsigned short* src =
        qkv + ((size_t)(b * TSEQ + kb_ * 64 + r)) * 3072 + 2048 + h * 64 + cq;
    u16x8 v0 = *(const u16x8*)src;
    u16x8 v1 = *(const u16x8*)(src + 8);
#pragma unroll
    for (int i = 0; i < 8; i++) T[r][cq + i] = v0[i];
#pragma unroll
    for (int i = 0; i < 8; i++) T[r][cq + 8 + i] = v1[i];
    __syncthreads();

    const int d = tid >> 2, kq = (tid & 3) * 16;
    u16x8 o0, o1;
#pragma unroll
    for (int i = 0; i < 8; i++) o0[i] = T[kq + i][d];
#pragma unroll
    for (int i = 0; i < 8; i++) o1[i] = T[kq + 8 + i][d];
    unsigned short* dst = vtg + ((size_t)bh * 64 + d) * TSEQ + kb_ * 64 + kq;
    *(u16x8*)dst = o0;
    *(u16x8*)(dst + 8) = o1;

    // per-tile V column sums (thread holds V[kq..kq+15][d])
    float ps = 0.f;
#pragma unroll
    for (int i = 0; i < 8; i++) ps += bf2f(o0[i]) + bf2f(o1[i]);
    ps += __shfl_xor(ps, 1);
    ps += __shfl_xor(ps, 2);
    if ((tid & 3) == 0)
        ts[((size_t)bh * 32 + kb_) * 64 + d] = ps;
}

// ---------------------------------------------------------------------------
// Suffix scan over tile sums: tsuf[bh][t][d] = sum_{t' > t} ts[bh][t'][d]
// ---------------------------------------------------------------------------
__global__ void vsuf2_kernel(const float* __restrict__ ts,
                             float* __restrict__ tsuf) {
    const int bh = blockIdx.x, d = threadIdx.x;
    float acc = 0.f;
    for (int t = 31; t >= 0; --t) {
        tsuf[((size_t)bh * 32 + t) * 64 + d] = acc;
        acc += ts[((size_t)bh * 32 + t) * 64 + d];
    }
}

// ---------------------------------------------------------------------------
// Attention v4: 4-wave blocks (128 q-rows), shared K/V^T tiles in LDS,
// double-buffered 2-phase pipeline (STAGE(t+1) issued before compute(t),
// one __syncthreads per tile). Tiles staged in FRAGMENT order so all LDS
// frag reads are contiguous conflict-free ds_read_b128.
// Mask semantics: logit = (k<=q) ? dot/8 : 0; exp2(0)=1 for masked entries,
// applied branchlessly every tile; tiles beyond block range via tsuf.
// ---------------------------------------------------------------------------
__global__ __launch_bounds__(256, 2)
void attn_kernel(const unsigned short* __restrict__ qkv,
                 const unsigned short* __restrict__ vtg,
                 const float* __restrict__ tsuf,
                 unsigned short* __restrict__ out) {
    __shared__ __attribute__((aligned(16))) unsigned short Ks[2][4096];
    __shared__ __attribute__((aligned(16))) unsigned short Vs[2][4096];
    __shared__ __attribute__((aligned(16))) unsigned short Pl[4][32 * 72];

    const int tid = threadIdx.x;
    const int w = tid >> 6, l = tid & 63, lr = l & 15, lg = l >> 4;
    const int bid = blockIdx.x;
    const int qb = 15 - (bid >> 5);                  // heavy q-blocks first
    const int bh = (bid & 7) * 4 + ((bid >> 3) & 3); // XCD-pinned (b,h)
    const int b = bh >> 4, h = bh & 15;
    const int ntiles = 2 * qb + 2;                   // k-tiles 0..2qb+1
    const size_t rowbase = (size_t)b * TSEQ;
    const int qrow0 = qb * 128 + w * 32;

    // Q fragments (A-operand)
    bf16x8 qf[2][2];
#pragma unroll
    for (int mi = 0; mi < 2; mi++) {
        const unsigned short* qp =
            qkv + (rowbase + qrow0 + mi * 16 + lr) * 3072 + h * 64 + lg * 8;
        qf[mi][0] = *(const bf16x8*)qp;
        qf[mi][1] = *(const bf16x8*)(qp + 32);
    }

    // staging source pointers, fragment order: d = tid + j*256,
    // f = d>>7, c = (d>>6)&1, ll = d&63; frag row f*16+(ll&15), col c*32+(ll>>4)*8
    const unsigned short* ksrc[2];
    const unsigned short* vsrc[2];
#pragma unroll
    for (int j = 0; j < 2; j++) {
        const int d = tid + j * 256;
        const int fr = (d >> 7) * 16 + (d & 15);
        const int cc = ((d >> 6) & 1) * 32 + ((d & 63) >> 4) * 8;
        ksrc[j] = qkv + (rowbase + fr) * 3072 + 1024 + h * 64 + cc;
        vsrc[j] = vtg + ((size_t)bh * 64 + fr) * TSEQ + cc;
    }

#define STAGE(kt_, bufi) do {                                      \
        const size_t ko_ = (size_t)(kt_) * 64 * 3072;              \
        const int vo_ = (kt_) * 64;                                \
        gld_lds16(ksrc[0] + ko_, &Ks[bufi][tid * 8]);              \
        gld_lds16(ksrc[1] + ko_, &Ks[bufi][tid * 8 + 2048]);       \
        gld_lds16(vsrc[0] + vo_, &Vs[bufi][tid * 8]);              \
        gld_lds16(vsrc[1] + vo_, &Vs[bufi][tid * 8 + 2048]);       \
    } while (0)

    f32x4 o[2][4] = {};
    float rsum[2][4] = {};
    unsigned short* pw = &Pl[w][0];

    STAGE(0, 0);
    __syncthreads();

    int cur = 0;
    for (int kt = 0; kt < ntiles; ++kt) {
        if (kt + 1 < ntiles) STAGE(kt + 1, cur ^ 1);

        const unsigned short* kc = Ks[cur];
        const unsigned short* vc = Vs[cur];

        // K frags (conflict-free contiguous b128)
        bf16x8 kb[4][2];
#pragma unroll
        for (int f = 0; f < 4; f++) {
            kb[f][0] = *(const bf16x8*)(kc + ((f * 2 + 0) * 64 + l) * 8);
            kb[f][1] = *(const bf16x8*)(kc + ((f * 2 + 1) * 64 + l) * 8);
        }

        // S = Q K^T
        float pvv[2][4][4];
        __builtin_amdgcn_s_setprio(1);
#pragma unroll
        for (int mi = 0; mi < 2; mi++)
#pragma unroll
            for (int f = 0; f < 4; f++) {
                f32x4 z = {0.f, 0.f, 0.f, 0.f};
                f32x4 s = __builtin_amdgcn_mfma_f32_16x16x32_bf16(qf[mi][0], kb[f][0], z, 0, 0, 0);
                s = __builtin_amdgcn_mfma_f32_16x16x32_bf16(qf[mi][1], kb[f][1], s, 0, 0, 0);
#pragma unroll
                for (int r = 0; r < 4; r++) pvv[mi][f][r] = s[r] * SC_LOG2E;
            }
        __builtin_amdgcn_s_setprio(0);

        // branchless tril zeroing + exp2 + row-sum partials + pack
#pragma unroll
        for (int mi = 0; mi < 2; mi++)
#pragma unroll
            for (int f = 0; f < 4; f++) {
                const int kcol = kt * 64 + f * 16 + lr;
#pragma unroll
                for (int r = 0; r < 4; r++) {
                    const int qr = qrow0 + mi * 16 + lg * 4 + r;
                    float sv = (kcol > qr) ? 0.f : pvv[mi][f][r];
                    float p = EXP2F(sv);
                    rsum[mi][r] += p;
                    pw[(mi * 16 + lg * 4 + r) * 72 + f * 16 + lr] = f2bf(p);
                }
            }

        // P relayout (same-wave LDS roundtrip) + V frags
        bf16x8 pa[2][2];
#pragma unroll
        for (int mi = 0; mi < 2; mi++) {
            pa[mi][0] = *(const bf16x8*)(pw + (mi * 16 + lr) * 72 + lg * 8);
            pa[mi][1] = *(const bf16x8*)(pw + (mi * 16 + lr) * 72 + 32 + lg * 8);
        }
        bf16x8 vb[4][2];
#pragma unroll
        for (int f2 = 0; f2 < 4; f2++) {
            vb[f2][0] = *(const bf16x8*)(vc + ((f2 * 2 + 0) * 64 + l) * 8);
            vb[f2][1] = *(const bf16x8*)(vc + ((f2 * 2 + 1) * 64 + l) * 8);
        }
        __builtin_amdgcn_s_setprio(1);
#pragma unroll
        for (int mi = 0; mi < 2; mi++)
#pragma unroll
            for (int f2 = 0; f2 < 4; f2++) {
                o[mi][f2] = __builtin_amdgcn_mfma_f32_16x16x32_bf16(pa[mi][0], vb[f2][0], o[mi][f2], 0, 0, 0);
                o[mi][f2] = __builtin_amdgcn_mfma_f32_16x16x32_bf16(pa[mi][1], vb[f2][1], o[mi][f2], 0, 0, 0);
            }
        __builtin_amdgcn_s_setprio(0);

        __syncthreads();
        cur ^= 1;
    }
#undef STAGE

    // row-sum reduce over the 16 lanes sharing a row
#pragma unroll
    for (int d = 1; d < 16; d <<= 1)
#pragma unroll
        for (int mi = 0; mi < 2; mi++)
#pragma unroll
            for (int r = 0; r < 4; r++)
                rsum[mi][r] += __shfl_xor(rsum[mi][r], d);

    // epilogue: closed-form future-tile part, normalize, store
    const int lastkt = ntiles - 1;
    const float nmask = (float)((31 - lastkt) * 64);
    const float* tp = tsuf + ((size_t)bh * 32 + lastkt) * 64;
#pragma unroll
    for (int mi = 0; mi < 2; mi++)
#pragma unroll
        for (int r = 0; r < 4; r++) {
            const float inv = 1.f / (rsum[mi][r] + nmask);
#pragma unroll
            for (int f2 = 0; f2 < 4; f2++) {
                float num = o[mi][f2][r] + tp[f2 * 16 + lr];
                out[(rowbase + qrow0 + mi * 16 + lg * 4 + r) * 1024 + h * 64 + f2 * 16 + lr] =
                    f2bf(num * inv);
            }
        }
}

// ---------------------------------------------------------------------------
extern "C" void kernel_launch(void* const* d_in, const int* in_sizes, int n_in,
                              void* d_out, int out_size, void* d_ws, size_t ws_size,
                              hipStream_t stream) {
    const float* x     = (const float*)d_in[0];
    const float* w_in  = (const float*)d_in[1];
    const float* w_out = (const float*)d_in[2];

    unsigned short* ws  = (unsigned short*)d_ws;
    unsigned short* xb  = ws;                            // 4096*1024
    unsigned short* wib = xb  + (size_t)4096 * 1024;     // 3072*1024
    unsigned short* wob = wib + (size_t)3072 * 1024;     // 1024*1024
    unsigned short* qkv = wob + (size_t)1024 * 1024;     // 4096*3072
    unsigned short* ao  = qkv + (size_t)4096 * 3072;     // 4096*1024
    float* tsuf = (float*)(ao + (size_t)4096 * 1024);    // 32*32*64 f32
    unsigned short* vtg = (unsigned short*)(tsuf + 32 * 32 * 64); // 32*64*2048
    float* ts = (float*)(vtg + (size_t)32 * 64 * 2048);  // 32*32*64 f32

    cast_f32_to_bf16<<<4096, 256, 0, stream>>>(x, xb, 4096 * 1024 / 4);
    cast_f32_to_bf16<<<3072, 256, 0, stream>>>(w_in, wib, 3072 * 1024 / 4);
    cast_f32_to_bf16<<<1024, 256, 0, stream>>>(w_out, wob, 1024 * 1024 / 4);

    gemm_bt<false><<<(4096 / 128) * (3072 / 128), 256, 0, stream>>>(
        xb, wib, qkv, 4096, 3072, 1024);
    vtran_kernel<<<32 * 32, 256, 0, stream>>>(qkv, vtg, ts);
    vsuf2_kernel<<<32, 64, 0, stream>>>(ts, tsuf);
    attn_kernel<<<512, 256, 0, stream>>>(qkv, vtg, tsuf, ao);
    gemm_bt<true><<<(4096 / 128) * (1024 / 128), 256, 0, stream>>>(
        ao, wob, (float*)d_out, 4096, 1024, 1024);
}

// Round 5
// 122.676 us; speedup vs baseline: 2.0407x; 1.0518x over previous
//
#include <hip/hip_runtime.h>
#include <hip/hip_bf16.h>
#include <stdint.h>

// Problem constants
#define TSEQ   2048
#define DMODEL 1024
#define NHEAD  16
#define HDIM   64

typedef __attribute__((ext_vector_type(8))) __bf16 bf16x8;
typedef __attribute__((ext_vector_type(4))) float f32x4;
typedef __attribute__((ext_vector_type(8))) unsigned short u16x8;

// log2(e)/8 : folds the 1/sqrt(64) logit scale into exp2
#define SC_LOG2E 0.18033688011112042f

#if __has_builtin(__builtin_amdgcn_exp2f)
#define EXP2F(x) __builtin_amdgcn_exp2f(x)
#else
#define EXP2F(x) __expf(0.6931471805599453f * (x))
#endif

__device__ __forceinline__ unsigned short f2bf(float f) {
    __hip_bfloat16 h = __float2bfloat16(f);
    return __builtin_bit_cast(unsigned short, h);
}
__device__ __forceinline__ float bf2f(unsigned short u) {
    union { unsigned int i; float f; } v;
    v.i = ((unsigned int)u) << 16;
    return v.f;
}

__device__ __forceinline__ void gld_lds16(const void* g, void* s) {
    __builtin_amdgcn_global_load_lds(
        (__attribute__((address_space(1))) void*)(void*)g,
        (__attribute__((address_space(3))) void*)s, 16, 0, 0);
}

// ---------------------------------------------------------------------------
// fused fp32 -> bf16 cast for x, w_in, w_out (one launch)
// ---------------------------------------------------------------------------
#define NX4  (4096 * 1024 / 4)
#define NWI4 (3072 * 1024 / 4)
#define NWO4 (1024 * 1024 / 4)
__global__ void cast3_kernel(const float* __restrict__ x,
                             const float* __restrict__ wi,
                             const float* __restrict__ wo,
                             unsigned short* __restrict__ ox,
                             unsigned short* __restrict__ owi,
                             unsigned short* __restrict__ owo) {
    int i = blockIdx.x * blockDim.x + threadIdx.x;
    const float* s;
    unsigned short* d;
    int off;
    if (i < NX4)              { s = x;  d = ox;  off = i; }
    else if (i < NX4 + NWI4)  { s = wi; d = owi; off = i - NX4; }
    else                      { s = wo; d = owo; off = i - NX4 - NWI4; }
    float4 v = ((const float4*)s)[off];
    ushort4 u;
    u.x = f2bf(v.x); u.y = f2bf(v.y); u.z = f2bf(v.z); u.w = f2bf(v.w);
    ((ushort4*)d)[off] = u;
}

// ---------------------------------------------------------------------------
// GEMM: C[m,n] = sum_k A[m,k] * B[n,k]   (A:[M,K] bf16, B:[N,K] bf16)
// ---------------------------------------------------------------------------
template<bool STORE_F32>
__global__ __launch_bounds__(256, 2)
void gemm_bt(const unsigned short* __restrict__ A,
             const unsigned short* __restrict__ B,
             void* __restrict__ C, int M, int N, int K) {
    (void)M;
    __shared__ unsigned short As[128 * 32];
    __shared__ unsigned short Bs[128 * 32];
    const int tid = threadIdx.x;
    const int nb = N >> 7;
    const int bm = blockIdx.x / nb;
    const int bn = blockIdx.x % nb;
    const int w  = tid >> 6, l = tid & 63;
    const int wr = w >> 1,  wc = w & 1;
    const int lr = l & 15,  lg = l >> 4;

    f32x4 acc[4][4] = {};

    const unsigned short* Ab = A + (size_t)bm * 128 * K;
    const unsigned short* Bb = B + (size_t)bn * 128 * K;

    const int c0 = tid, c1 = tid + 256;
    const int ar0 = c0 >> 2, ak0 = (c0 & 3) * 8;
    const int ar1 = c1 >> 2, ak1 = (c1 & 3) * 8;

    for (int kt = 0; kt < K; kt += 32) {
        __syncthreads();
        gld_lds16(Ab + (size_t)ar0 * K + kt + ak0, As + c0 * 8);
        gld_lds16(Ab + (size_t)ar1 * K + kt + ak1, As + c1 * 8);
        gld_lds16(Bb + (size_t)ar0 * K + kt + ak0, Bs + c0 * 8);
        gld_lds16(Bb + (size_t)ar1 * K + kt + ak1, Bs + c1 * 8);
        __syncthreads();

        bf16x8 af[4], bfr[4];
#pragma unroll
        for (int i = 0; i < 4; i++)
            af[i] = *(const bf16x8*)(As + (wr * 64 + i * 16 + lr) * 32 + lg * 8);
#pragma unroll
        for (int i = 0; i < 4; i++)
            bfr[i] = *(const bf16x8*)(Bs + (wc * 64 + i * 16 + lr) * 32 + lg * 8);
#pragma unroll
        for (int mi = 0; mi < 4; mi++)
#pragma unroll
            for (int ni = 0; ni < 4; ni++)
                acc[mi][ni] = __builtin_amdgcn_mfma_f32_16x16x32_bf16(
                    af[mi], bfr[ni], acc[mi][ni], 0, 0, 0);
    }

    const int row0 = bm * 128 + wr * 64;
    const int col0 = bn * 128 + wc * 64;
#pragma unroll
    for (int mi = 0; mi < 4; mi++)
#pragma unroll
        for (int ni = 0; ni < 4; ni++)
#pragma unroll
            for (int r = 0; r < 4; r++) {
                const int row = row0 + mi * 16 + lg * 4 + r;
                const int col = col0 + ni * 16 + lr;
                if (STORE_F32)
                    ((float*)C)[(size_t)row * N + col] = acc[mi][ni][r];
                else
                    ((unsigned short*)C)[(size_t)row * N + col] = f2bf(acc[mi][ni][r]);
            }
}

// ---------------------------------------------------------------------------
// V transpose + per-tile column sums:
//   VTg[bh][d][k] = V[b][k][h*64+d]
//   ts[bh][t][d]  = sum_{k in tile t} V[k][d]
// ---------------------------------------------------------------------------
__global__ __launch_bounds__(256)
void vtran_kernel(const unsigned short* __restrict__ qkv,
                  unsigned short* __restrict__ vtg,
                  float* __restrict__ ts) {
    __shared__ unsigned short T[64][72];
    const int bid = blockIdx.x;
    const int kb_ = bid & 31;
    const int bh  = bid >> 5;
    const int b = bh >> 4, h = bh & 15;
    const int tid = threadIdx.x;

    const int r = tid >> 2, cq = (tid & 3) * 16;
    const unsigned short* src =
        qkv + ((size_t)(b * TSEQ + kb_ * 64 + r)) * 3072 + 2048 + h * 64 + cq;
    u16x8 v0 = *(const u16x8*)src;
    u16x8 v1 = *(const u16x8*)(src + 8);
#pragma unroll
    for (int i = 0; i < 8; i++) T[r][cq + i] = v0[i];
#pragma unroll
    for (int i = 0; i < 8; i++) T[r][cq + 8 + i] = v1[i];
    __syncthreads();

    const int d = tid >> 2, kq = (tid & 3) * 16;
    u16x8 o0, o1;
#pragma unroll
    for (int i = 0; i < 8; i++) o0[i] = T[kq + i][d];
#pragma unroll
    for (int i = 0; i < 8; i++) o1[i] = T[kq + 8 + i][d];
    unsigned short* dst = vtg + ((size_t)bh * 64 + d) * TSEQ + kb_ * 64 + kq;
    *(u16x8*)dst = o0;
    *(u16x8*)(dst + 8) = o1;

    // per-tile V column sums (thread holds V[kq..kq+15][d])
    float ps = 0.f;
#pragma unroll
    for (int i = 0; i < 8; i++) ps += bf2f(o0[i]) + bf2f(o1[i]);
    ps += __shfl_xor(ps, 1);
    ps += __shfl_xor(ps, 2);
    if ((tid & 3) == 0)
        ts[((size_t)bh * 32 + kb_) * 64 + d] = ps;
}

// ---------------------------------------------------------------------------
// Suffix scan over tile sums: tsuf[bh][t][d] = sum_{t' > t} ts[bh][t'][d]
// ---------------------------------------------------------------------------
__global__ void vsuf2_kernel(const float* __restrict__ ts,
                             float* __restrict__ tsuf) {
    const int bh = blockIdx.x, d = threadIdx.x;
    float acc = 0.f;
    for (int t = 31; t >= 0; --t) {
        tsuf[((size_t)bh * 32 + t) * 64 + d] = acc;
        acc += ts[((size_t)bh * 32 + t) * 64 + d];
    }
}

// ---------------------------------------------------------------------------
// Attention v5: strip-paired load-balanced 4-wave blocks.
// Block j covers q-strips (p, 31-p), p = j<8 ? j : 23-j  (64 rows each).
// Waves 0,1 -> long strip (31-p); waves 2,3 -> short strip (p); each wave
// computes only k-tiles <= its own diagonal and closes the rest via tsuf
// (masked logits are 0 -> exp(0)=1 -> uniform V colsum contribution).
// Per-block compute = 33 wave-tile-pairs (constant); CU-paired blocks
// (bid, bid+256) have complementary loop lengths (49 total).
// ---------------------------------------------------------------------------
__global__ __launch_bounds__(256, 2)
void attn_kernel(const unsigned short* __restrict__ qkv,
                 const unsigned short* __restrict__ vtg,
                 const float* __restrict__ tsuf,
                 unsigned short* __restrict__ out) {
    __shared__ __attribute__((aligned(16))) unsigned short Ks[2][4096];
    __shared__ __attribute__((aligned(16))) unsigned short Vs[2][4096];
    __shared__ __attribute__((aligned(16))) unsigned short Pl[4][32 * 72];

    const int tid = threadIdx.x;
    const int w = tid >> 6, l = tid & 63, lr = l & 15, lg = l >> 4;
    const int bid = blockIdx.x;
    const int j  = bid >> 5;
    const int p  = (j < 8) ? j : 23 - j;             // strip pair (p, 31-p)
    const int bh = (bid & 7) * 4 + ((bid >> 3) & 3); // XCD-pinned (b,h)
    const int b = bh >> 4, h = bh & 15;
    const int strip  = (w < 2) ? (31 - p) : p;       // this wave's 64-row strip
    const int lastkt = strip;                        // wave's diagonal k-tile
    const int ntiles = 32 - p;                       // staged tiles (long strip)
    const size_t rowbase = (size_t)b * TSEQ;
    const int qrow0 = strip * 64 + (w & 1) * 32;

    // Q fragments (A-operand)
    bf16x8 qf[2][2];
#pragma unroll
    for (int mi = 0; mi < 2; mi++) {
        const unsigned short* qp =
            qkv + (rowbase + qrow0 + mi * 16 + lr) * 3072 + h * 64 + lg * 8;
        qf[mi][0] = *(const bf16x8*)qp;
        qf[mi][1] = *(const bf16x8*)(qp + 32);
    }

    // staging source pointers, fragment order
    const unsigned short* ksrc[2];
    const unsigned short* vsrc[2];
#pragma unroll
    for (int jj = 0; jj < 2; jj++) {
        const int d = tid + jj * 256;
        const int fr = (d >> 7) * 16 + (d & 15);
        const int cc = ((d >> 6) & 1) * 32 + ((d & 63) >> 4) * 8;
        ksrc[jj] = qkv + (rowbase + fr) * 3072 + 1024 + h * 64 + cc;
        vsrc[jj] = vtg + ((size_t)bh * 64 + fr) * TSEQ + cc;
    }

#define STAGE(kt_, bufi) do {                                      \
        const size_t ko_ = (size_t)(kt_) * 64 * 3072;              \
        const int vo_ = (kt_) * 64;                                \
        gld_lds16(ksrc[0] + ko_, &Ks[bufi][tid * 8]);              \
        gld_lds16(ksrc[1] + ko_, &Ks[bufi][tid * 8 + 2048]);       \
        gld_lds16(vsrc[0] + vo_, &Vs[bufi][tid * 8]);              \
        gld_lds16(vsrc[1] + vo_, &Vs[bufi][tid * 8 + 2048]);       \
    } while (0)

    f32x4 o[2][4] = {};
    float rsum[2][4] = {};
    unsigned short* pw = &Pl[w][0];

    STAGE(0, 0);
    __syncthreads();

    int cur = 0;
    for (int kt = 0; kt < ntiles; ++kt) {
        if (kt + 1 < ntiles) STAGE(kt + 1, cur ^ 1);

        if (kt <= lastkt) {   // wave-uniform: skip tiles past this strip's diag
            const unsigned short* kc = Ks[cur];
            const unsigned short* vc = Vs[cur];

            bf16x8 kb[4][2];
#pragma unroll
            for (int f = 0; f < 4; f++) {
                kb[f][0] = *(const bf16x8*)(kc + ((f * 2 + 0) * 64 + l) * 8);
                kb[f][1] = *(const bf16x8*)(kc + ((f * 2 + 1) * 64 + l) * 8);
            }

            float pvv[2][4][4];
            __builtin_amdgcn_s_setprio(1);
#pragma unroll
            for (int mi = 0; mi < 2; mi++)
#pragma unroll
                for (int f = 0; f < 4; f++) {
                    f32x4 z = {0.f, 0.f, 0.f, 0.f};
                    f32x4 s = __builtin_amdgcn_mfma_f32_16x16x32_bf16(qf[mi][0], kb[f][0], z, 0, 0, 0);
                    s = __builtin_amdgcn_mfma_f32_16x16x32_bf16(qf[mi][1], kb[f][1], s, 0, 0, 0);
#pragma unroll
                    for (int r = 0; r < 4; r++) pvv[mi][f][r] = s[r] * SC_LOG2E;
                }
            __builtin_amdgcn_s_setprio(0);

            // branchless tril zeroing + exp2 + row-sum partials + pack
#pragma unroll
            for (int mi = 0; mi < 2; mi++)
#pragma unroll
                for (int f = 0; f < 4; f++) {
                    const int kcol = kt * 64 + f * 16 + lr;
#pragma unroll
                    for (int r = 0; r < 4; r++) {
                        const int qr = qrow0 + mi * 16 + lg * 4 + r;
                        float sv = (kcol > qr) ? 0.f : pvv[mi][f][r];
                        float pp = EXP2F(sv);
                        rsum[mi][r] += pp;
                        pw[(mi * 16 + lg * 4 + r) * 72 + f * 16 + lr] = f2bf(pp);
                    }
                }

            bf16x8 pa[2][2];
#pragma unroll
            for (int mi = 0; mi < 2; mi++) {
                pa[mi][0] = *(const bf16x8*)(pw + (mi * 16 + lr) * 72 + lg * 8);
                pa[mi][1] = *(const bf16x8*)(pw + (mi * 16 + lr) * 72 + 32 + lg * 8);
            }
            bf16x8 vb[4][2];
#pragma unroll
            for (int f2 = 0; f2 < 4; f2++) {
                vb[f2][0] = *(const bf16x8*)(vc + ((f2 * 2 + 0) * 64 + l) * 8);
                vb[f2][1] = *(const bf16x8*)(vc + ((f2 * 2 + 1) * 64 + l) * 8);
            }
            __builtin_amdgcn_s_setprio(1);
#pragma unroll
            for (int mi = 0; mi < 2; mi++)
#pragma unroll
                for (int f2 = 0; f2 < 4; f2++) {
                    o[mi][f2] = __builtin_amdgcn_mfma_f32_16x16x32_bf16(pa[mi][0], vb[f2][0], o[mi][f2], 0, 0, 0);
                    o[mi][f2] = __builtin_amdgcn_mfma_f32_16x16x32_bf16(pa[mi][1], vb[f2][1], o[mi][f2], 0, 0, 0);
                }
            __builtin_amdgcn_s_setprio(0);
        }

        __syncthreads();
        cur ^= 1;
    }
#undef STAGE

    // row-sum reduce over the 16 lanes sharing a row
#pragma unroll
    for (int d = 1; d < 16; d <<= 1)
#pragma unroll
        for (int mi = 0; mi < 2; mi++)
#pragma unroll
            for (int r = 0; r < 4; r++)
                rsum[mi][r] += __shfl_xor(rsum[mi][r], d);

    // epilogue: closed-form future-tile part (per-wave), normalize, store
    const float nmask = (float)((31 - lastkt) * 64);
    const float* tp = tsuf + ((size_t)bh * 32 + lastkt) * 64;
#pragma unroll
    for (int mi = 0; mi < 2; mi++)
#pragma unroll
        for (int r = 0; r < 4; r++) {
            const float inv = 1.f / (rsum[mi][r] + nmask);
#pragma unroll
            for (int f2 = 0; f2 < 4; f2++) {
                float num = o[mi][f2][r] + tp[f2 * 16 + lr];
                out[(rowbase + qrow0 + mi * 16 + lg * 4 + r) * 1024 + h * 64 + f2 * 16 + lr] =
                    f2bf(num * inv);
            }
        }
}

// ---------------------------------------------------------------------------
extern "C" void kernel_launch(void* const* d_in, const int* in_sizes, int n_in,
                              void* d_out, int out_size, void* d_ws, size_t ws_size,
                              hipStream_t stream) {
    const float* x     = (const float*)d_in[0];
    const float* w_in  = (const float*)d_in[1];
    const float* w_out = (const float*)d_in[2];

    unsigned short* ws  = (unsigned short*)d_ws;
    unsigned short* xb  = ws;                            // 4096*1024
    unsigned short* wib = xb  + (size_t)4096 * 1024;     // 3072*1024
    unsigned short* wob = wib + (size_t)3072 * 1024;     // 1024*1024
    unsigned short* qkv = wob + (size_t)1024 * 1024;     // 4096*3072
    unsigned short* ao  = qkv + (size_t)4096 * 3072;     // 4096*1024
    float* tsuf = (float*)(ao + (size_t)4096 * 1024);    // 32*32*64 f32
    unsigned short* vtg = (unsigned short*)(tsuf + 32 * 32 * 64); // 32*64*2048
    float* ts = (float*)(vtg + (size_t)32 * 64 * 2048);  // 32*32*64 f32

    cast3_kernel<<<(NX4 + NWI4 + NWO4) / 256, 256, 0, stream>>>(
        x, w_in, w_out, xb, wib, wob);

    gemm_bt<false><<<(4096 / 128) * (3072 / 128), 256, 0, stream>>>(
        xb, wib, qkv, 4096, 3072, 1024);
    vtran_kernel<<<32 * 32, 256, 0, stream>>>(qkv, vtg, ts);
    vsuf2_kernel<<<32, 64, 0, stream>>>(ts, tsuf);
    attn_kernel<<<512, 256, 0, stream>>>(qkv, vtg, tsuf, ao);
    gemm_bt<true><<<(4096 / 128) * (1024 / 128), 256, 0, stream>>>(
        ao, wob, (float*)d_out, 4096, 1024, 1024);
}